// Round 16
// baseline (236.932 us; speedup 1.0000x reference)
//
#include <hip/hip_runtime.h>

#define N_NODES 10000
#define N_EDGES 320000
#define F 256          // F_IN == F_OUT
#define K2 512         // 2*F_IN
#define SLOTS 96       // per-node bucket capacity (deg ~Poisson(32); P(>96) ~ 0)
#define N_TILE16 625   // 10000/16 exactly
#define W_BLOCKS 128      // F*K2/4/256
#define CNT_BLOCKS 10     // 10*256 = 2560 >= 2500 int4
#define CONV_BLOCKS 2500  // N*F/4/256
#define SCAT_BLOCKS 1250  // 1 edge/thread
// Diagnostic repeat factors (idempotent kernels only)
#define REP_PREP 16
#define REP_CONV 16
#define REP_AGG 8
#define REP_GEMM 8

typedef __attribute__((ext_vector_type(8))) __bf16 bf16x8;
typedef __attribute__((ext_vector_type(4))) __bf16 bf16x4;
typedef __attribute__((ext_vector_type(4))) float f32x4;
typedef __attribute__((ext_vector_type(2))) float f32x2;
typedef unsigned long long u64;
typedef unsigned int u32;
typedef unsigned short u16;

// Wt layout: Wt[t][kq][col][8e], t=k/32, kq=(k%32)/8, e=k%8 (fragment-contiguous).

// ---------- K1 (x16): Wt (h0 folded) + cnt = 0
__global__ __launch_bounds__(256) void prep_kernel(
    const float* __restrict__ feat,
    const float* __restrict__ Wm,
    const int* __restrict__ src,
    __bf16* __restrict__ Wt,
    int* __restrict__ cnt) {
  int b = blockIdx.x;
  int tid = threadIdx.x;
#pragma unroll 1
  for (int rep = 0; rep < REP_PREP; ++rep) {
    if (b < W_BLOCKS) {
      int idx = b * 256 + tid;                 // float4 index over W
      int o_ = idx >> 7;                       // 128 float4 per W row
      int k = (idx & 127) * 4;
      float4 w = ((const float4*)Wm)[idx];
      if (k >= F) {
        int s0 = src[0];
        float4 h = ((const float4*)(feat + (size_t)s0 * F))[(k - F) >> 2];
        w.x *= h.x; w.y *= h.y; w.z *= h.z; w.w *= h.w;
      }
      bf16x4 o;
      o[0] = (__bf16)w.x; o[1] = (__bf16)w.y; o[2] = (__bf16)w.z; o[3] = (__bf16)w.w;
      int t = k >> 5, kq = (k & 31) >> 3, e = k & 7;
      size_t offT = (((size_t)t * 4 + kq) * 256 + o_) * 8 + e;
      *(bf16x4*)(Wt + offT) = o;
    } else {
      int idx = (b - W_BLOCKS) * 256 + tid;
      if (idx < N_NODES / 4) ((int4*)cnt)[idx] = make_int4(0, 0, 0, 0);
    }
    asm volatile("" ::: "memory");
  }
}

// ---------- K2 (x16): feat -> fp8 conversion only
__global__ __launch_bounds__(256) void conv_kernel(
    const float* __restrict__ feat,
    u32* __restrict__ feat8) {
  int idx = blockIdx.x * 256 + threadIdx.x;    // float4 index over feat
#pragma unroll 1
  for (int rep = 0; rep < REP_CONV; ++rep) {
    float4 v = ((const float4*)feat)[idx];
    u32 r8 = 0;
    r8 = __builtin_amdgcn_cvt_pk_fp8_f32(v.x, v.y, r8, false);
    r8 = __builtin_amdgcn_cvt_pk_fp8_f32(v.z, v.w, r8, true);
    feat8[idx] = r8;
    asm volatile("" ::: "memory");
  }
}

// ---------- K3 (x1): bucket scatter, 1 edge/thread (5000 waves)
__global__ __launch_bounds__(256) void scatter_kernel(
    const int* __restrict__ src,
    const int* __restrict__ dst,
    const float* __restrict__ ew,
    int* __restrict__ cnt,
    u32* __restrict__ bucket) {
  int e = blockIdx.x * 256 + threadIdx.x;
  if (e >= N_EDGES) return;
  int d = dst[e];
  u32 wb = (__float_as_uint(ew[e]) + 0x8000u) & 0xFFFF0000u;   // RNE-ish bf16
  int p = atomicAdd(&cnt[d], 1);
  if (p < SLOTS) bucket[(size_t)d * SLOTS + p] = wb | (u32)src[e];
}

// ---------- K4 (x8): aggregation over fp8 rows (R14 body: 1 wave/node)
__global__ __launch_bounds__(256) void node_agg_kernel(
    const u32* __restrict__ feat8,
    const u32* __restrict__ bucket,
    const int* __restrict__ cnt,
    __bf16* __restrict__ aggb) {
  int node = (blockIdx.x * 256 + threadIdx.x) >> 6;
  int lane = threadIdx.x & 63;
  if (node >= N_NODES) return;
  const uint2* frow = (const uint2*)feat8;   // row = 32 x 8B granules (8 fp8 each)
  const int half = lane >> 5;                // edge parity this lane handles
  const int slot = lane & 31;                // 8B granule within row
#pragma unroll 1
  for (int rep = 0; rep < REP_AGG; ++rep) {
    int c = cnt[node];
    int cc = min(c, SLOTS);
    const u32* bk = bucket + (size_t)node * SLOTS;
    float acc[8];
#pragma unroll
    for (int e = 0; e < 8; ++e) acc[e] = 0.f;

    for (int i = 0; i < cc; i += 16) {
      u32 p[8];
      uint2 v[8];
#pragma unroll
      for (int j = 0; j < 8; ++j) {
        int e = i + half + 2 * j;
        p[j] = bk[min(e, cc - 1)];
      }
#pragma unroll
      for (int j = 0; j < 8; ++j)
        v[j] = frow[(size_t)(p[j] & 0xFFFFu) * 32 + slot];
#pragma unroll
      for (int j = 0; j < 8; ++j) {
        int e = i + half + 2 * j;
        float w = (e < cc) ? __uint_as_float(p[j] & 0xFFFF0000u) : 0.f;
        f32x2 f01 = __builtin_amdgcn_cvt_pk_f32_fp8(v[j].x, false);
        f32x2 f23 = __builtin_amdgcn_cvt_pk_f32_fp8(v[j].x, true);
        f32x2 f45 = __builtin_amdgcn_cvt_pk_f32_fp8(v[j].y, false);
        f32x2 f67 = __builtin_amdgcn_cvt_pk_f32_fp8(v[j].y, true);
        acc[0] += f01[0] * w; acc[1] += f01[1] * w;
        acc[2] += f23[0] * w; acc[3] += f23[1] * w;
        acc[4] += f45[0] * w; acc[5] += f45[1] * w;
        acc[6] += f67[0] * w; acc[7] += f67[1] * w;
      }
    }

#pragma unroll
    for (int e = 0; e < 8; ++e) acc[e] += __shfl_xor(acc[e], 32, 64);

    if (half == 0) {
      float ic = 1.0f / (float)max(c, 1);
      bf16x8 o;
#pragma unroll
      for (int e = 0; e < 8; ++e) o[e] = (__bf16)(acc[e] * ic);
      *(bf16x8*)(aggb + (size_t)node * F + slot * 8) = o;
    }
    asm volatile("" ::: "memory");
  }
}

// ---------- K5 (x8): split-K MFMA GEMM (R14 body). 625 blocks x 8 waves.
__global__ __launch_bounds__(512) void mfma_gemm_kernel(
    const float* __restrict__ feat,     // [N][F] f32
    const __bf16* __restrict__ aggb,    // [N][F] bf16
    const __bf16* __restrict__ Wt,      // [16][4][256][8]
    const float* __restrict__ bias,
    float* __restrict__ out) {          // [N][F]
  __shared__ float part[4 * 64 * 17];   // stride 17 dwords: conflict-free b32s

  const int tid = threadIdx.x;
  const int wave = tid >> 6;
  const int lane = tid & 63;
  const int kh = wave >> 2;             // K-half
  const int cw = wave & 3;              // col wave
  const int r15 = lane & 15;
  const int kq = lane >> 4;
  const int col0 = cw * 64;
  const int m0 = blockIdx.x * 16;       // 625*16 == 10000 exactly

#pragma unroll 1
  for (int rep = 0; rep < REP_GEMM; ++rep) {
    f32x4 acc[4];
#pragma unroll
    for (int cs = 0; cs < 4; ++cs) acc[cs] = (f32x4){0.f, 0.f, 0.f, 0.f};

    if (kh == 0) {
      const float* arow = feat + (size_t)(m0 + r15) * F;
#pragma unroll
      for (int t = 0; t < 8; ++t) {
        float4 lo = *(const float4*)(arow + t * 32 + kq * 8);
        float4 hi = *(const float4*)(arow + t * 32 + kq * 8 + 4);
        bf16x8 a;
        a[0] = (__bf16)lo.x; a[1] = (__bf16)lo.y; a[2] = (__bf16)lo.z; a[3] = (__bf16)lo.w;
        a[4] = (__bf16)hi.x; a[5] = (__bf16)hi.y; a[6] = (__bf16)hi.z; a[7] = (__bf16)hi.w;
#pragma unroll
        for (int cs = 0; cs < 4; ++cs) {
          bf16x8 bb = *(const bf16x8*)(Wt + (((size_t)t * 4 + kq) * 256 + col0 + cs * 16 + r15) * 8);
          acc[cs] = __builtin_amdgcn_mfma_f32_16x16x32_bf16(a, bb, acc[cs], 0, 0, 0);
        }
      }
    } else {
      const __bf16* arow = aggb + (size_t)(m0 + r15) * F;
#pragma unroll
      for (int t2 = 0; t2 < 8; ++t2) {
        bf16x8 a = *(const bf16x8*)(arow + t2 * 32 + kq * 8);
#pragma unroll
        for (int cs = 0; cs < 4; ++cs) {
          bf16x8 bb = *(const bf16x8*)(Wt + (((size_t)(t2 + 8) * 4 + kq) * 256 + col0 + cs * 16 + r15) * 8);
          acc[cs] = __builtin_amdgcn_mfma_f32_16x16x32_bf16(a, bb, acc[cs], 0, 0, 0);
        }
      }
      float* dstp = &part[(cw * 64 + lane) * 17];
#pragma unroll
      for (int cs = 0; cs < 4; ++cs)
#pragma unroll
        for (int r = 0; r < 4; ++r) dstp[cs * 4 + r] = acc[cs][r];
    }
    __syncthreads();

    if (kh == 0) {
      const float* srcp = &part[(cw * 64 + lane) * 17];
      const int rbase = kq * 4;
#pragma unroll
      for (int cs = 0; cs < 4; ++cs) {
        int col = col0 + cs * 16 + r15;
        float bv = bias[col];
#pragma unroll
        for (int r = 0; r < 4; ++r) {
          int orow = m0 + rbase + r;
          float v = acc[cs][r] + srcp[cs * 4 + r] + bv;
          out[(size_t)orow * F + col] = fmaxf(v, 0.0f);
        }
      }
    }
    __syncthreads();
    asm volatile("" ::: "memory");
  }
}

extern "C" void kernel_launch(void* const* d_in, const int* in_sizes, int n_in,
                              void* d_out, int out_size, void* d_ws, size_t ws_size,
                              hipStream_t stream) {
  const float* feat = (const float*)d_in[0];
  const float* ew   = (const float*)d_in[1];
  const int*   src  = (const int*)d_in[2];
  const int*   dst  = (const int*)d_in[3];
  const float* Wm   = (const float*)d_in[4];
  const float* bias = (const float*)d_in[5];
  float* out = (float*)d_out;

  // workspace layout (all 16B-aligned sizes)
  u32*    bucket = (u32*)d_ws;                                   // N*SLOTS  (3.84 MB)
  __bf16* aggb   = (__bf16*)(bucket + (size_t)N_NODES * SLOTS);  // N*F      (5.12 MB)
  __bf16* Wt     = aggb + (size_t)N_NODES * F;                   // F*K2     (0.26 MB)
  u32*    feat8  = (u32*)(Wt + (size_t)F * K2);                  // N*F/4    (2.56 MB)
  int*    cnt    = (int*)(feat8 + (size_t)N_NODES * F / 4);      // N

  prep_kernel<<<W_BLOCKS + CNT_BLOCKS, 256, 0, stream>>>(feat, Wm, src, Wt, cnt);
  conv_kernel<<<CONV_BLOCKS, 256, 0, stream>>>(feat, feat8);
  scatter_kernel<<<SCAT_BLOCKS, 256, 0, stream>>>(src, dst, ew, cnt, bucket);
  node_agg_kernel<<<(N_NODES * 64 + 255) / 256, 256, 0, stream>>>(feat8, bucket, cnt, aggb);
  mfma_gemm_kernel<<<N_TILE16, 512, 0, stream>>>(feat, aggb, Wt, bias, out);
}

// Round 17
// 63.868 us; speedup vs baseline: 3.7097x; 3.7097x over previous
//
#include <hip/hip_runtime.h>

#define N_NODES 10000
#define N_EDGES 320000
#define F 256          // F_IN == F_OUT
#define K2 512         // 2*F_IN
#define SLOTS 96       // per-node bucket capacity (deg ~Poisson(32); P(>96) ~ 0)
#define N_TILE16 625   // 10000/16 exactly
#define W_BLOCKS 128      // F*K2/4/256
#define CNT_BLOCKS 10     // 10*256 = 2560 >= 2500 int4
#define CONV_BLOCKS 2500  // N*F/4/256
#define PREP_BLOCKS (W_BLOCKS + CNT_BLOCKS + CONV_BLOCKS)
#define SCAT_BLOCKS 1250  // 1 edge/thread -> one atomic round-trip per thread

typedef __attribute__((ext_vector_type(8))) __bf16 bf16x8;
typedef __attribute__((ext_vector_type(4))) __bf16 bf16x4;
typedef __attribute__((ext_vector_type(4))) float f32x4;
typedef __attribute__((ext_vector_type(2))) float f32x2;
typedef unsigned long long u64;
typedef unsigned int u32;
typedef unsigned short u16;

// Wt layout: Wt[t][kq][col][8e], t=k/32, kq=(k%32)/8, e=k%8 (fragment-contiguous).

// ---------- K1: Wt (h0 folded) + cnt=0 + feat->fp8  (one wide grid)
__global__ __launch_bounds__(256) void prep_conv_kernel(
    const float* __restrict__ feat,
    const float* __restrict__ Wm,
    const int* __restrict__ src,
    __bf16* __restrict__ Wt,
    int* __restrict__ cnt,
    u32* __restrict__ feat8) {
  int b = blockIdx.x;
  int tid = threadIdx.x;
  if (b < W_BLOCKS) {
    int idx = b * 256 + tid;                 // float4 index over W
    int o_ = idx >> 7;                       // 128 float4 per W row
    int k = (idx & 127) * 4;
    float4 w = ((const float4*)Wm)[idx];
    if (k >= F) {
      int s0 = src[0];
      float4 h = ((const float4*)(feat + (size_t)s0 * F))[(k - F) >> 2];
      w.x *= h.x; w.y *= h.y; w.z *= h.z; w.w *= h.w;
    }
    bf16x4 o;
    o[0] = (__bf16)w.x; o[1] = (__bf16)w.y; o[2] = (__bf16)w.z; o[3] = (__bf16)w.w;
    int t = k >> 5, kq = (k & 31) >> 3, e = k & 7;
    size_t offT = (((size_t)t * 4 + kq) * 256 + o_) * 8 + e;
    *(bf16x4*)(Wt + offT) = o;
  } else if (b < W_BLOCKS + CNT_BLOCKS) {
    int idx = (b - W_BLOCKS) * 256 + tid;
    if (idx < N_NODES / 4) ((int4*)cnt)[idx] = make_int4(0, 0, 0, 0);
  } else {
    int idx = (b - W_BLOCKS - CNT_BLOCKS) * 256 + tid;  // float4 index over feat
    float4 v = ((const float4*)feat)[idx];
    u32 r8 = 0;
    r8 = __builtin_amdgcn_cvt_pk_fp8_f32(v.x, v.y, r8, false);
    r8 = __builtin_amdgcn_cvt_pk_fp8_f32(v.z, v.w, r8, true);
    feat8[idx] = r8;
  }
}

// ---------- K2: bucket scatter, 1 edge/thread (5000 waves, max TLP)
__global__ __launch_bounds__(256) void scatter_kernel(
    const int* __restrict__ src,
    const int* __restrict__ dst,
    const float* __restrict__ ew,
    int* __restrict__ cnt,
    u32* __restrict__ bucket) {
  int e = blockIdx.x * 256 + threadIdx.x;
  if (e >= N_EDGES) return;
  int d = dst[e];
  u32 wb = (__float_as_uint(ew[e]) + 0x8000u) & 0xFFFF0000u;   // RNE-ish bf16
  int p = atomicAdd(&cnt[d], 1);
  if (p < SLOTS) bucket[(size_t)d * SLOTS + p] = wb | (u32)src[e];
}

// ---------- K3: aggregation over fp8 rows (1 wave/node, paired-lane 8B gathers)
__global__ __launch_bounds__(256) void node_agg_kernel(
    const u32* __restrict__ feat8,
    const u32* __restrict__ bucket,
    const int* __restrict__ cnt,
    __bf16* __restrict__ aggb) {
  int node = (blockIdx.x * 256 + threadIdx.x) >> 6;
  int lane = threadIdx.x & 63;
  if (node >= N_NODES) return;
  int c = cnt[node];
  int cc = min(c, SLOTS);
  const u32* bk = bucket + (size_t)node * SLOTS;
  const uint2* frow = (const uint2*)feat8;   // row = 32 x 8B granules (8 fp8 each)
  const int half = lane >> 5;                // edge parity this lane handles
  const int slot = lane & 31;                // 8B granule within row

  float acc[8];
#pragma unroll
  for (int e = 0; e < 8; ++e) acc[e] = 0.f;

  for (int i = 0; i < cc; i += 16) {
    u32 p[8];
    uint2 v[8];
#pragma unroll
    for (int j = 0; j < 8; ++j) {
      int e = i + half + 2 * j;
      p[j] = bk[min(e, cc - 1)];
    }
#pragma unroll
    for (int j = 0; j < 8; ++j)
      v[j] = frow[(size_t)(p[j] & 0xFFFFu) * 32 + slot];
#pragma unroll
    for (int j = 0; j < 8; ++j) {
      int e = i + half + 2 * j;
      float w = (e < cc) ? __uint_as_float(p[j] & 0xFFFF0000u) : 0.f;
      f32x2 f01 = __builtin_amdgcn_cvt_pk_f32_fp8(v[j].x, false);
      f32x2 f23 = __builtin_amdgcn_cvt_pk_f32_fp8(v[j].x, true);
      f32x2 f45 = __builtin_amdgcn_cvt_pk_f32_fp8(v[j].y, false);
      f32x2 f67 = __builtin_amdgcn_cvt_pk_f32_fp8(v[j].y, true);
      acc[0] += f01[0] * w; acc[1] += f01[1] * w;
      acc[2] += f23[0] * w; acc[3] += f23[1] * w;
      acc[4] += f45[0] * w; acc[5] += f45[1] * w;
      acc[6] += f67[0] * w; acc[7] += f67[1] * w;
    }
  }

#pragma unroll
  for (int e = 0; e < 8; ++e) acc[e] += __shfl_xor(acc[e], 32, 64);

  if (half == 0) {
    float ic = 1.0f / (float)max(c, 1);
    bf16x8 o;
#pragma unroll
    for (int e = 0; e < 8; ++e) o[e] = (__bf16)(acc[e] * ic);
    *(bf16x8*)(aggb + (size_t)node * F + slot * 8) = o;
  }
}

// ---------- K4: split-K MFMA GEMM (R14 body, confirmed 16.3 us)
__global__ __launch_bounds__(512) void mfma_gemm_kernel(
    const float* __restrict__ feat,     // [N][F] f32
    const __bf16* __restrict__ aggb,    // [N][F] bf16
    const __bf16* __restrict__ Wt,      // [16][4][256][8]
    const float* __restrict__ bias,
    float* __restrict__ out) {          // [N][F]
  __shared__ float part[4 * 64 * 17];   // stride 17 dwords: conflict-free b32s

  const int tid = threadIdx.x;
  const int wave = tid >> 6;
  const int lane = tid & 63;
  const int kh = wave >> 2;             // K-half
  const int cw = wave & 3;              // col wave
  const int r15 = lane & 15;
  const int kq = lane >> 4;
  const int col0 = cw * 64;
  const int m0 = blockIdx.x * 16;       // 625*16 == 10000 exactly

  f32x4 acc[4];
#pragma unroll
  for (int cs = 0; cs < 4; ++cs) acc[cs] = (f32x4){0.f, 0.f, 0.f, 0.f};

  if (kh == 0) {
    const float* arow = feat + (size_t)(m0 + r15) * F;
#pragma unroll
    for (int t = 0; t < 8; ++t) {
      float4 lo = *(const float4*)(arow + t * 32 + kq * 8);
      float4 hi = *(const float4*)(arow + t * 32 + kq * 8 + 4);
      bf16x8 a;
      a[0] = (__bf16)lo.x; a[1] = (__bf16)lo.y; a[2] = (__bf16)lo.z; a[3] = (__bf16)lo.w;
      a[4] = (__bf16)hi.x; a[5] = (__bf16)hi.y; a[6] = (__bf16)hi.z; a[7] = (__bf16)hi.w;
#pragma unroll
      for (int cs = 0; cs < 4; ++cs) {
        bf16x8 bb = *(const bf16x8*)(Wt + (((size_t)t * 4 + kq) * 256 + col0 + cs * 16 + r15) * 8);
        acc[cs] = __builtin_amdgcn_mfma_f32_16x16x32_bf16(a, bb, acc[cs], 0, 0, 0);
      }
    }
  } else {
    const __bf16* arow = aggb + (size_t)(m0 + r15) * F;
#pragma unroll
    for (int t2 = 0; t2 < 8; ++t2) {
      bf16x8 a = *(const bf16x8*)(arow + t2 * 32 + kq * 8);
#pragma unroll
      for (int cs = 0; cs < 4; ++cs) {
        bf16x8 bb = *(const bf16x8*)(Wt + (((size_t)(t2 + 8) * 4 + kq) * 256 + col0 + cs * 16 + r15) * 8);
        acc[cs] = __builtin_amdgcn_mfma_f32_16x16x32_bf16(a, bb, acc[cs], 0, 0, 0);
      }
    }
    float* dstp = &part[(cw * 64 + lane) * 17];
#pragma unroll
    for (int cs = 0; cs < 4; ++cs)
#pragma unroll
      for (int r = 0; r < 4; ++r) dstp[cs * 4 + r] = acc[cs][r];
  }
  __syncthreads();

  if (kh == 0) {
    const float* srcp = &part[(cw * 64 + lane) * 17];
    const int rbase = kq * 4;
#pragma unroll
    for (int cs = 0; cs < 4; ++cs) {
      int col = col0 + cs * 16 + r15;
      float bv = bias[col];
#pragma unroll
      for (int r = 0; r < 4; ++r) {
        int orow = m0 + rbase + r;
        float v = acc[cs][r] + srcp[cs * 4 + r] + bv;
        out[(size_t)orow * F + col] = fmaxf(v, 0.0f);
      }
    }
  }
}

extern "C" void kernel_launch(void* const* d_in, const int* in_sizes, int n_in,
                              void* d_out, int out_size, void* d_ws, size_t ws_size,
                              hipStream_t stream) {
  const float* feat = (const float*)d_in[0];
  const float* ew   = (const float*)d_in[1];
  const int*   src  = (const int*)d_in[2];
  const int*   dst  = (const int*)d_in[3];
  const float* Wm   = (const float*)d_in[4];
  const float* bias = (const float*)d_in[5];
  float* out = (float*)d_out;

  // workspace layout (all 16B-aligned sizes)
  u32*    bucket = (u32*)d_ws;                                   // N*SLOTS  (3.84 MB)
  __bf16* aggb   = (__bf16*)(bucket + (size_t)N_NODES * SLOTS);  // N*F      (5.12 MB)
  __bf16* Wt     = aggb + (size_t)N_NODES * F;                   // F*K2     (0.26 MB)
  u32*    feat8  = (u32*)(Wt + (size_t)F * K2);                  // N*F/4    (2.56 MB)
  int*    cnt    = (int*)(feat8 + (size_t)N_NODES * F / 4);      // N

  prep_conv_kernel<<<PREP_BLOCKS, 256, 0, stream>>>(feat, Wm, src, Wt, cnt, feat8);
  scatter_kernel<<<SCAT_BLOCKS, 256, 0, stream>>>(src, dst, ew, cnt, bucket);
  node_agg_kernel<<<(N_NODES * 64 + 255) / 256, 256, 0, stream>>>(feat8, bucket, cnt, aggb);
  mfma_gemm_kernel<<<N_TILE16, 512, 0, stream>>>(feat, aggb, Wt, bias, out);
}

// Round 18
// 57.682 us; speedup vs baseline: 4.1075x; 1.1072x over previous
//
#include <hip/hip_runtime.h>

#define N_NODES 10000
#define N_EDGES 320000
#define F 256          // F_IN == F_OUT
#define K2 512         // 2*F_IN
#define SLOTS 96       // per-node bucket capacity (deg ~Poisson(32); P(>96) ~ 0)
#define CSTR 16        // cnt stride in ints: one counter per 64B line (anti-contention)
#define N_TILE16 625   // 10000/16 exactly
#define W_BLOCKS 128      // F*K2/4/256
#define CNT_BLOCKS 625    // (N_NODES*CSTR/4)/256 = 156.25 -> 625 covers 160000 int4
#define CONV_BLOCKS 2500  // N*F/4/256
#define PREP_BLOCKS (W_BLOCKS + CNT_BLOCKS + CONV_BLOCKS)
#define SCAT_BLOCKS 1250  // 1 edge/thread

typedef __attribute__((ext_vector_type(8))) __bf16 bf16x8;
typedef __attribute__((ext_vector_type(4))) __bf16 bf16x4;
typedef __attribute__((ext_vector_type(4))) float f32x4;
typedef __attribute__((ext_vector_type(2))) float f32x2;
typedef unsigned long long u64;
typedef unsigned int u32;
typedef unsigned short u16;

// Wt layout: Wt[t][kq][col][8e], t=k/32, kq=(k%32)/8, e=k%8 (fragment-contiguous).

// ---------- K1: Wt (h0 folded) + cnt=0 (padded) + feat->fp8  (one wide grid)
__global__ __launch_bounds__(256) void prep_conv_kernel(
    const float* __restrict__ feat,
    const float* __restrict__ Wm,
    const int* __restrict__ src,
    __bf16* __restrict__ Wt,
    int* __restrict__ cnt,
    u32* __restrict__ feat8) {
  int b = blockIdx.x;
  int tid = threadIdx.x;
  if (b < W_BLOCKS) {
    int idx = b * 256 + tid;                 // float4 index over W
    int o_ = idx >> 7;                       // 128 float4 per W row
    int k = (idx & 127) * 4;
    float4 w = ((const float4*)Wm)[idx];
    if (k >= F) {
      int s0 = src[0];
      float4 h = ((const float4*)(feat + (size_t)s0 * F))[(k - F) >> 2];
      w.x *= h.x; w.y *= h.y; w.z *= h.z; w.w *= h.w;
    }
    bf16x4 o;
    o[0] = (__bf16)w.x; o[1] = (__bf16)w.y; o[2] = (__bf16)w.z; o[3] = (__bf16)w.w;
    int t = k >> 5, kq = (k & 31) >> 3, e = k & 7;
    size_t offT = (((size_t)t * 4 + kq) * 256 + o_) * 8 + e;
    *(bf16x4*)(Wt + offT) = o;
  } else if (b < W_BLOCKS + CNT_BLOCKS) {
    int idx = (b - W_BLOCKS) * 256 + tid;    // int4 index over padded cnt
    if (idx < N_NODES * CSTR / 4) ((int4*)cnt)[idx] = make_int4(0, 0, 0, 0);
  } else {
    int idx = (b - W_BLOCKS - CNT_BLOCKS) * 256 + tid;  // float4 index over feat
    float4 v = ((const float4*)feat)[idx];
    u32 r8 = 0;
    r8 = __builtin_amdgcn_cvt_pk_fp8_f32(v.x, v.y, r8, false);
    r8 = __builtin_amdgcn_cvt_pk_fp8_f32(v.z, v.w, r8, true);
    feat8[idx] = r8;
  }
}

// ---------- K2: bucket scatter, 1 edge/thread; line-private counters
__global__ __launch_bounds__(256) void scatter_kernel(
    const int* __restrict__ src,
    const int* __restrict__ dst,
    const float* __restrict__ ew,
    int* __restrict__ cnt,
    u32* __restrict__ bucket) {
  int e = blockIdx.x * 256 + threadIdx.x;
  if (e >= N_EDGES) return;
  int d = dst[e];
  u32 wb = (__float_as_uint(ew[e]) + 0x8000u) & 0xFFFF0000u;   // RNE-ish bf16
  int p = atomicAdd(&cnt[d * CSTR], 1);
  if (p < SLOTS) bucket[(size_t)d * SLOTS + p] = wb | (u32)src[e];
}

// ---------- K3: aggregation over fp8 rows (1 wave/node, paired-lane 8B gathers)
__global__ __launch_bounds__(256) void node_agg_kernel(
    const u32* __restrict__ feat8,
    const u32* __restrict__ bucket,
    const int* __restrict__ cnt,
    __bf16* __restrict__ aggb) {
  int node = (blockIdx.x * 256 + threadIdx.x) >> 6;
  int lane = threadIdx.x & 63;
  if (node >= N_NODES) return;
  int c = cnt[node * CSTR];
  int cc = min(c, SLOTS);
  const u32* bk = bucket + (size_t)node * SLOTS;
  const uint2* frow = (const uint2*)feat8;   // row = 32 x 8B granules (8 fp8 each)
  const int half = lane >> 5;                // edge parity this lane handles
  const int slot = lane & 31;                // 8B granule within row

  float acc[8];
#pragma unroll
  for (int e = 0; e < 8; ++e) acc[e] = 0.f;

  for (int i = 0; i < cc; i += 16) {
    u32 p[8];
    uint2 v[8];
#pragma unroll
    for (int j = 0; j < 8; ++j) {
      int e = i + half + 2 * j;
      p[j] = bk[min(e, cc - 1)];
    }
#pragma unroll
    for (int j = 0; j < 8; ++j)
      v[j] = frow[(size_t)(p[j] & 0xFFFFu) * 32 + slot];
#pragma unroll
    for (int j = 0; j < 8; ++j) {
      int e = i + half + 2 * j;
      float w = (e < cc) ? __uint_as_float(p[j] & 0xFFFF0000u) : 0.f;
      f32x2 f01 = __builtin_amdgcn_cvt_pk_f32_fp8(v[j].x, false);
      f32x2 f23 = __builtin_amdgcn_cvt_pk_f32_fp8(v[j].x, true);
      f32x2 f45 = __builtin_amdgcn_cvt_pk_f32_fp8(v[j].y, false);
      f32x2 f67 = __builtin_amdgcn_cvt_pk_f32_fp8(v[j].y, true);
      acc[0] += f01[0] * w; acc[1] += f01[1] * w;
      acc[2] += f23[0] * w; acc[3] += f23[1] * w;
      acc[4] += f45[0] * w; acc[5] += f45[1] * w;
      acc[6] += f67[0] * w; acc[7] += f67[1] * w;
    }
  }

#pragma unroll
  for (int e = 0; e < 8; ++e) acc[e] += __shfl_xor(acc[e], 32, 64);

  if (half == 0) {
    float ic = 1.0f / (float)max(c, 1);
    bf16x8 o;
#pragma unroll
    for (int e = 0; e < 8; ++e) o[e] = (__bf16)(acc[e] * ic);
    *(bf16x8*)(aggb + (size_t)node * F + slot * 8) = o;
  }
}

// ---------- K4: split-K MFMA GEMM (R14 body, measured 16.3 us)
__global__ __launch_bounds__(512) void mfma_gemm_kernel(
    const float* __restrict__ feat,     // [N][F] f32
    const __bf16* __restrict__ aggb,    // [N][F] bf16
    const __bf16* __restrict__ Wt,      // [16][4][256][8]
    const float* __restrict__ bias,
    float* __restrict__ out) {          // [N][F]
  __shared__ float part[4 * 64 * 17];   // stride 17 dwords: conflict-free b32s

  const int tid = threadIdx.x;
  const int wave = tid >> 6;
  const int lane = tid & 63;
  const int kh = wave >> 2;             // K-half
  const int cw = wave & 3;              // col wave
  const int r15 = lane & 15;
  const int kq = lane >> 4;
  const int col0 = cw * 64;
  const int m0 = blockIdx.x * 16;       // 625*16 == 10000 exactly

  f32x4 acc[4];
#pragma unroll
  for (int cs = 0; cs < 4; ++cs) acc[cs] = (f32x4){0.f, 0.f, 0.f, 0.f};

  if (kh == 0) {
    const float* arow = feat + (size_t)(m0 + r15) * F;
#pragma unroll
    for (int t = 0; t < 8; ++t) {
      float4 lo = *(const float4*)(arow + t * 32 + kq * 8);
      float4 hi = *(const float4*)(arow + t * 32 + kq * 8 + 4);
      bf16x8 a;
      a[0] = (__bf16)lo.x; a[1] = (__bf16)lo.y; a[2] = (__bf16)lo.z; a[3] = (__bf16)lo.w;
      a[4] = (__bf16)hi.x; a[5] = (__bf16)hi.y; a[6] = (__bf16)hi.z; a[7] = (__bf16)hi.w;
#pragma unroll
      for (int cs = 0; cs < 4; ++cs) {
        bf16x8 bb = *(const bf16x8*)(Wt + (((size_t)t * 4 + kq) * 256 + col0 + cs * 16 + r15) * 8);
        acc[cs] = __builtin_amdgcn_mfma_f32_16x16x32_bf16(a, bb, acc[cs], 0, 0, 0);
      }
    }
  } else {
    const __bf16* arow = aggb + (size_t)(m0 + r15) * F;
#pragma unroll
    for (int t2 = 0; t2 < 8; ++t2) {
      bf16x8 a = *(const bf16x8*)(arow + t2 * 32 + kq * 8);
#pragma unroll
      for (int cs = 0; cs < 4; ++cs) {
        bf16x8 bb = *(const bf16x8*)(Wt + (((size_t)(t2 + 8) * 4 + kq) * 256 + col0 + cs * 16 + r15) * 8);
        acc[cs] = __builtin_amdgcn_mfma_f32_16x16x32_bf16(a, bb, acc[cs], 0, 0, 0);
      }
    }
    float* dstp = &part[(cw * 64 + lane) * 17];
#pragma unroll
    for (int cs = 0; cs < 4; ++cs)
#pragma unroll
      for (int r = 0; r < 4; ++r) dstp[cs * 4 + r] = acc[cs][r];
  }
  __syncthreads();

  if (kh == 0) {
    const float* srcp = &part[(cw * 64 + lane) * 17];
    const int rbase = kq * 4;
#pragma unroll
    for (int cs = 0; cs < 4; ++cs) {
      int col = col0 + cs * 16 + r15;
      float bv = bias[col];
#pragma unroll
      for (int r = 0; r < 4; ++r) {
        int orow = m0 + rbase + r;
        float v = acc[cs][r] + srcp[cs * 4 + r] + bv;
        out[(size_t)orow * F + col] = fmaxf(v, 0.0f);
      }
    }
  }
}

extern "C" void kernel_launch(void* const* d_in, const int* in_sizes, int n_in,
                              void* d_out, int out_size, void* d_ws, size_t ws_size,
                              hipStream_t stream) {
  const float* feat = (const float*)d_in[0];
  const float* ew   = (const float*)d_in[1];
  const int*   src  = (const int*)d_in[2];
  const int*   dst  = (const int*)d_in[3];
  const float* Wm   = (const float*)d_in[4];
  const float* bias = (const float*)d_in[5];
  float* out = (float*)d_out;

  // workspace layout (all 16B-aligned sizes)
  u32*    bucket = (u32*)d_ws;                                   // N*SLOTS  (3.84 MB)
  __bf16* aggb   = (__bf16*)(bucket + (size_t)N_NODES * SLOTS);  // N*F      (5.12 MB)
  __bf16* Wt     = aggb + (size_t)N_NODES * F;                   // F*K2     (0.26 MB)
  u32*    feat8  = (u32*)(Wt + (size_t)F * K2);                  // N*F/4    (2.56 MB)
  int*    cnt    = (int*)(feat8 + (size_t)N_NODES * F / 4);      // N*CSTR   (0.64 MB)

  prep_conv_kernel<<<PREP_BLOCKS, 256, 0, stream>>>(feat, Wm, src, Wt, cnt, feat8);
  scatter_kernel<<<SCAT_BLOCKS, 256, 0, stream>>>(src, dst, ew, cnt, bucket);
  node_agg_kernel<<<(N_NODES * 64 + 255) / 256, 256, 0, stream>>>(feat8, bucket, cnt, aggb);
  mfma_gemm_kernel<<<N_TILE16, 512, 0, stream>>>(feat, aggb, Wt, bias, out);
}